// Round 6
// baseline (118.770 us; speedup 1.0000x reference)
//
#include <hip/hip_runtime.h>
#include <hip/hip_bf16.h>
#include <math.h>

#define B_ 64
#define L_ 2048
#define V_ 50000
#define E_ 300
#define H_ 128
#define C_ 10
#define NGB 782            // tiles of 64 rows
#define GB 256             // persistent gemm blocks (1/CU)

// ws layout (bytes):
//     0: mm[2] (encoded min/max)      8: cnt[2] (done counters)
//    16: bitmap[1563] (6252 B)
//  8192: cArr[2048] f32   16384: pArr[2048] f32   24576: SArr[128] f32
// 25088: pooled[64][128] f32 (32 KB)
// 65536: embW1 bf16 [50000][128] (12.8 MB)

typedef short bf16x8 __attribute__((ext_vector_type(8)));
typedef float f32x4 __attribute__((ext_vector_type(4)));

__device__ __forceinline__ unsigned enc_f32(float f) {
  unsigned u = __float_as_uint(f);
  return (u & 0x80000000u) ? ~u : (u | 0x80000000u);
}
__device__ __forceinline__ float dec_f32(unsigned u) {
  unsigned v = (u & 0x80000000u) ? (u ^ 0x80000000u) : ~u;
  return __uint_as_float(v);
}
__device__ __forceinline__ unsigned short f2bf(float f) {  // RNE f32->bf16
  unsigned u = __float_as_uint(f);
  unsigned r = 0x7FFFu + ((u >> 16) & 1u);
  return (unsigned short)((u + r) >> 16);
}

// ---- K0: init mm + counters + zero bitmap ----
__global__ __launch_bounds__(512) void k_init(unsigned* __restrict__ mm,
                                              unsigned* __restrict__ cnt,
                                              unsigned* __restrict__ bm) {
  const int t = threadIdx.x;
  if (t == 0) { mm[0] = 0xFFFFFFFFu; mm[1] = 0u; cnt[0] = 0u; cnt[1] = 0u; }
  for (int i = t; i < 1563; i += 512) bm[i] = 0u;
}

// ---- K1: presence bitmap of tokens ----
__global__ __launch_bounds__(256) void k_bitmap(const int* __restrict__ x,
                                                unsigned* __restrict__ bm) {
  const int i = blockIdx.x * 256 + threadIdx.x;   // 512 blocks cover B_*L_
  const int v = x[i];
  atomicOr(&bm[v >> 5], 1u << (v & 31));
}

// ---- K2: persistent embW1 = bf16(emb @ W1) + present-min/max; last block
//      runs the Newton c/P scan + SArr (fused k_scan). ----
__global__ __launch_bounds__(512) void k_gemm(
    const float* __restrict__ emb, const float* __restrict__ W1,
    const unsigned* __restrict__ bm, unsigned* __restrict__ mm,
    unsigned short* __restrict__ embW1, unsigned* __restrict__ cnt,
    const float* __restrict__ alphaP, const float* __restrict__ betaP,
    float* __restrict__ cArr, float* __restrict__ pArr,
    float* __restrict__ SArr) {
  __shared__ unsigned short at[2][32][328];   // double-buffered bf16 subtile
  __shared__ float smn[8], smx[8];
  __shared__ float lmn, lmx;
  __shared__ bool lastf;
  const int bid = blockIdx.x;
  const int tid = threadIdx.x;
  const int w = tid >> 6, lane = tid & 63;
  const int arow = lane & 15, g = lane >> 4;
  const int rr = tid >> 4, c16 = tid & 15;     // staging: 32 rows x 16 thr/row

  const int nt = (bid < NGB - 3 * GB) ? 4 : 3; // 782 = 3*256 + 14
  const int ns = nt * 2;                       // subtiles of 32 rows

  // W1^T fragments (A operand, m-dim = h-col), loaded once per block
  bf16x8 bfr[10];
  const int col = w * 16 + arow;
#pragma unroll
  for (int kt = 0; kt < 10; ++kt) {
    const int k0 = kt * 32 + g * 8;
#pragma unroll
    for (int i = 0; i < 8; ++i) {
      const int k = k0 + i;
      bfr[kt][i] = (short)((k < E_) ? f2bf(W1[k * H_ + col]) : 0);
    }
  }

  float mn = 3.4e38f, mx = -3.4e38f;

  auto rowbase = [&](int s) { return (bid + (s >> 1) * GB) * 64 + (s & 1) * 32; };
  auto issue = [&](int s, float4 (&pf)[5]) {
    const int row = rowbase(s) + rr;
    const float* rp = emb + (size_t)((row < V_) ? row : (V_ - 1)) * E_;
#pragma unroll
    for (int j = 0; j < 5; ++j) {
      const int k0 = c16 * 4 + 64 * j;
      pf[j] = (k0 < E_) ? *(const float4*)(rp + k0) : float4{0, 0, 0, 0};
    }
  };
  auto stage = [&](int s, float4 (&pf)[5]) {
    const int row = rowbase(s) + rr;
    const bool pres = (row < V_) && ((bm[row >> 5] >> (row & 31)) & 1u);
#pragma unroll
    for (int j = 0; j < 5; ++j) {
      const int k0 = c16 * 4 + 64 * j;
      const float4 v = pf[j];
      if (pres && k0 < E_) {
        mn = fminf(mn, fminf(fminf(v.x, v.y), fminf(v.z, v.w)));
        mx = fmaxf(mx, fmaxf(fmaxf(v.x, v.y), fmaxf(v.z, v.w)));
      }
      unsigned long long p = 0ull;
      if (k0 < E_)
        p = (unsigned long long)f2bf(v.x) | ((unsigned long long)f2bf(v.y) << 16)
          | ((unsigned long long)f2bf(v.z) << 32) | ((unsigned long long)f2bf(v.w) << 48);
      *(unsigned long long*)&at[s & 1][rr][k0] = p;
    }
  };

  float4 pfA[5], pfB[5];
  issue(0, pfA);
  if (ns > 1) issue(1, pfB);

  for (int s = 0; s < ns; ++s) {
    if (s & 1) { stage(s, pfB); if (s + 2 < ns) issue(s + 2, pfB); }
    else       { stage(s, pfA); if (s + 2 < ns) issue(s + 2, pfA); }
    __syncthreads();   // subtile s staged; also guards buf reuse (see note)
    const int r0s = rowbase(s);
#pragma unroll
    for (int rt = 0; rt < 2; ++rt) {
      f32x4 acc = {0, 0, 0, 0};
#pragma unroll
      for (int kt = 0; kt < 10; ++kt) {
        bf16x8 bb = *(const bf16x8*)&at[s & 1][rt * 16 + arow][kt * 32 + g * 8];
        acc = __builtin_amdgcn_mfma_f32_16x16x32_bf16(bfr[kt], bb, acc, 0, 0, 0);
      }
      const int grow = r0s + rt * 16 + arow;
      if (grow < V_) {
        unsigned long long p = (unsigned long long)f2bf(acc[0])
                             | ((unsigned long long)f2bf(acc[1]) << 16)
                             | ((unsigned long long)f2bf(acc[2]) << 32)
                             | ((unsigned long long)f2bf(acc[3]) << 48);
        *(unsigned long long*)&embW1[(size_t)grow * H_ + w * 16 + g * 4] = p;
      }
    }
    // no trailing barrier: next overwrite of this buffer is 2 subtiles away,
    // separated by the next iteration's barrier.
  }

  // ---- block min/max -> global atomics; last block -> scan ----
#pragma unroll
  for (int s = 1; s < 64; s <<= 1) {
    mn = fminf(mn, __shfl_xor(mn, s));
    mx = fmaxf(mx, __shfl_xor(mx, s));
  }
  if (lane == 0) { smn[w] = mn; smx[w] = mx; }
  __syncthreads();
  if (tid == 0) {
#pragma unroll
    for (int i = 1; i < 8; ++i) { mn = fminf(mn, smn[i]); mx = fmaxf(mx, smx[i]); }
    atomicMin(&mm[0], enc_f32(mn));
    atomicMax(&mm[1], enc_f32(mx));
    __threadfence();
    lastf = (atomicAdd(&cnt[0], 1u) == GB - 1u);
  }
  __syncthreads();
  if (!lastf) return;

  // ===== fused k_scan (runs once, in the last-finishing block) =====
  if (tid == 0) {
    lmn = dec_f32(atomicOr(&mm[0], 0u));
    lmx = dec_f32(atomicOr(&mm[1], 0u));
  }
  __syncthreads();
  if (tid < 64) {
    const int ln = tid;
    const float alpha = alphaP[0];
    const float sb = betaP[0] * lmn / (lmx - lmn);   // -beta*xn(xe=0)
    const float tl = (float)(ln * 32);

    float c = sqrtf(fmaf(2.0f * alpha, tl, 1.0f));
    if (fabsf(sb) > 1e-7f) {
      const float isb = 1.0f / sb;
      const float k2 = alpha * isb * isb;
      const float d0 = fmaxf(alpha + sb, 1e-8f);
#pragma unroll
      for (int it = 0; it < 4; ++it) {
        const float den = fmaxf(fmaf(sb, c, alpha), 1e-8f);
        const float T = (c - 1.0f) * isb - k2 * logf(den / d0);
        c = c - (T - tl) * den / c;
        c = fminf(fmaxf(c, 1.0f), 1e3f);
      }
    }
    if (ln == 0) c = 1.0f;

#pragma unroll
    for (int sw = 0; sw < 3; ++sw) {
      float cc = c, d = 1.0f;
#pragma unroll
      for (int j = 0; j < 32; ++j) {
        const float r = __builtin_amdgcn_rcpf(cc);
        d *= fmaf(-alpha * r, r, 1.0f);
        cc = fmaf(alpha, r, cc) + sb;
      }
      float A = d, Bv = fmaf(-d, c, cc);
#pragma unroll
      for (int o = 1; o < 64; o <<= 1) {
        const float A2 = __shfl_up(A, o);
        const float B2 = __shfl_up(Bv, o);
        if (ln >= o) { Bv = fmaf(A, B2, Bv); A *= A2; }
      }
      const float As = __shfl_up(A, 1);
      const float Bs = __shfl_up(Bv, 1);
      if (ln > 0) c = As + Bs;
    }

    float av[32];
    float cc = c, Q = 1.0f;
#pragma unroll
    for (int j = 0; j < 32; ++j) {
      cArr[ln * 32 + j] = cc;
      const float r = __builtin_amdgcn_rcpf(cc);
      const float a = fmaf(-alpha * r, r, 1.0f);
      av[j] = a; Q *= a;
      cc = fmaf(alpha, r, cc) + sb;
    }
    float Pp = Q;
#pragma unroll
    for (int o = 1; o < 64; o <<= 1) {
      const float q2 = __shfl_up(Pp, o);
      if (ln >= o) Pp *= q2;
    }
    const float Ps = __shfl_up(Pp, 1);
    float P = (ln == 0) ? 1.0f : Ps;
#pragma unroll
    for (int j = 0; j < 32; ++j) {
      pArr[ln * 32 + j] = P;
      P *= av[j];
    }
  } else if (tid < 192) {
    const int cl = tid - 64;
    float s = 0.0f;
    for (int k = 0; k < E_; ++k) s += W1[k * H_ + cl];
    SArr[cl] = s;
  }
}

// ---- K3: per-b prefix + z-max + tanh; last block does pooled @ W2 + b2 ----
__global__ __launch_bounds__(1024) void k_pref(
    const int* __restrict__ x, const unsigned short* __restrict__ embW1,
    const float* __restrict__ cArr, const float* __restrict__ pArr,
    const float* __restrict__ SArr, const float* __restrict__ b1,
    const float* __restrict__ betaP, const unsigned* __restrict__ mm,
    float* __restrict__ pooled, unsigned* __restrict__ cnt,
    const float* __restrict__ W2, const float* __restrict__ b2,
    float* __restrict__ out) {
  __shared__ int xls[L_];
  __shared__ float part[16][128];
  __shared__ float wmax[16][128];
  __shared__ bool lastf;
  const int b = blockIdx.x;
  const int tid = threadIdx.x;
  const int wv = tid >> 6, lane = tid & 63;
  for (int i = tid; i < L_; i += 1024) xls[i] = x[b * L_ + i];
  const float mn = dec_f32(mm[0]), mx = dec_f32(mm[1]);
  const float binv = betaP[0] / (mx - mn);
  const int t0 = wv * 128;
  const int col2 = lane * 2;
  __syncthreads();

  // pass 1: segment partial sums of q_s * y_s
  float s0 = 0.0f, s1 = 0.0f;
#pragma unroll 4
  for (int j = 0; j < 128; ++j) {
    const int t = t0 + j;
    const unsigned y2 = *(const unsigned*)(embW1 + (size_t)xls[t] * H_ + col2);
    const float q = (t + 1 < L_) ? __builtin_amdgcn_rcpf(pArr[t + 1]) : 0.0f;
    s0 = fmaf(q, __uint_as_float(y2 << 16), s0);
    s1 = fmaf(q, __uint_as_float(y2 & 0xFFFF0000u), s1);
  }
  part[wv][col2] = s0; part[wv][col2 + 1] = s1;
  __syncthreads();
  float m0 = 0.0f, m1 = 0.0f;
  for (int wp = 0; wp < wv; ++wp) { m0 += part[wp][col2]; m1 += part[wp][col2 + 1]; }

  // pass 2: z_t = c_t*S - binv*P_t*m_t ; running max (m updated AFTER z)
  float z0m = -3.4e38f, z1m = -3.4e38f;
  const float S0 = SArr[col2], S1 = SArr[col2 + 1];
#pragma unroll 4
  for (int j = 0; j < 128; ++j) {
    const int t = t0 + j;
    const unsigned y2 = *(const unsigned*)(embW1 + (size_t)xls[t] * H_ + col2);
    const float ct = cArr[t];
    const float gt = binv * pArr[t];
    const float q = (t + 1 < L_) ? __builtin_amdgcn_rcpf(pArr[t + 1]) : 0.0f;
    z0m = fmaxf(z0m, fmaf(-gt, m0, ct * S0));
    z1m = fmaxf(z1m, fmaf(-gt, m1, ct * S1));
    m0 = fmaf(q, __uint_as_float(y2 << 16), m0);
    m1 = fmaf(q, __uint_as_float(y2 & 0xFFFF0000u), m1);
  }
  wmax[wv][col2] = z0m; wmax[wv][col2 + 1] = z1m;
  __syncthreads();
  if (tid < H_) {
    float mz = wmax[0][tid];
#pragma unroll
    for (int w2 = 1; w2 < 16; ++w2) mz = fmaxf(mz, wmax[w2][tid]);
    pooled[b * H_ + tid] = tanhf(mz + b1[tid]);
    __threadfence();            // make pooled row device-visible before signal
  }
  __syncthreads();
  if (tid == 0) lastf = (atomicAdd(&cnt[1], 1u) == B_ - 1u);
  __syncthreads();
  if (lastf && tid < B_ * C_) {
    const int bb = tid / C_, c = tid % C_;
    float s = b2[c];
#pragma unroll 8
    for (int k = 0; k < H_; ++k) s = fmaf(pooled[bb * H_ + k], W2[k * C_ + c], s);
    out[tid] = s;
  }
}

extern "C" void kernel_launch(void* const* d_in, const int* in_sizes, int n_in,
                              void* d_out, int out_size, void* d_ws, size_t ws_size,
                              hipStream_t stream) {
  const int* x = (const int*)d_in[0];
  const float* emb = (const float*)d_in[1];
  const float* alpha = (const float*)d_in[2];
  const float* beta = (const float*)d_in[3];
  const float* W1 = (const float*)d_in[4];
  const float* b1 = (const float*)d_in[5];
  const float* W2 = (const float*)d_in[6];
  const float* b2 = (const float*)d_in[7];
  (void)in_sizes; (void)n_in; (void)out_size; (void)ws_size;

  char* ws = (char*)d_ws;
  unsigned* mm = (unsigned*)ws;
  unsigned* cnt = (unsigned*)(ws + 8);
  unsigned* bm = (unsigned*)(ws + 16);
  float* cArr = (float*)(ws + 8192);
  float* pArr = (float*)(ws + 16384);
  float* SArr = (float*)(ws + 24576);
  float* pooled = (float*)(ws + 25088);
  unsigned short* embW1 = (unsigned short*)(ws + 65536);

  k_init<<<1, 512, 0, stream>>>(mm, cnt, bm);
  k_bitmap<<<(B_ * L_) / 256, 256, 0, stream>>>(x, bm);
  k_gemm<<<GB, 512, 0, stream>>>(emb, W1, bm, mm, embW1, cnt,
                                 alpha, beta, cArr, pArr, SArr);
  k_pref<<<B_, 1024, 0, stream>>>(x, embW1, cArr, pArr, SArr, b1, beta, mm,
                                  pooled, cnt, W2, b2, (float*)d_out);
}